// Round 8
// baseline (396.928 us; speedup 1.0000x reference)
//
#include <hip/hip_runtime.h>
#include <math.h>

#define N 512
#define CS 384
#define CZ 128
#define CH 16
#define NH 12
#define PQ 4
#define PV 8

// workspace layout (float offsets)
#define OFF_Q     0          // 512*192
#define OFF_K     98304      // 512*192
#define OFF_V     196608     // 512*192
#define OFF_QRAW  294912     // 512*144
#define OFF_KVRAW 368640     // 512*432
#define OFF_QPTS  589824     // 512*144
#define OFF_KPTS  663552     // 512*144
#define OFF_VPTS  737280     // 512*288 AoS: [n][h*PV+p][xyz]
#define OFF_A     884736     // 512*12*512 = 3145728  (A0 logits -> probs -> out partials)
#define OFF_CAT   4030464    // 512*2112
// end = 5111808 floats

// ---------------- kernel 1: fused projections, 64-col tiles for 2x blocks ----------------
__global__ __launch_bounds__(256) void proj_kernel(
    const float* __restrict__ s,
    const float* __restrict__ Wq,  const float* __restrict__ bq,
    const float* __restrict__ Wkv, const float* __restrict__ bkv,
    const float* __restrict__ Wqp, const float* __restrict__ bqp,
    const float* __restrict__ Wkvp,const float* __restrict__ bkvp,
    float* __restrict__ ws)
{
    __shared__ float st[16 * CS];   // 24 KB
    const int n0 = blockIdx.x * 16;
    for (int idx = threadIdx.x * 4; idx < 16 * CS; idx += 256 * 4)
        *(float4*)&st[idx] = *(const float4*)&s[n0 * CS + idx];
    __syncthreads();

    const int tc = threadIdx.x & 15;       // 16 col-quads -> 64 cols
    const int tr = threadIdx.x >> 4;       // 16 rows, 1 row/thread
    const int u0 = blockIdx.y * 64 + tc * 4;

    const float* W; const float* bptr; int ncol, lc0;
    if (u0 < 192)      { W = Wq;   bptr = bq;   ncol = 192; lc0 = u0; }
    else if (u0 < 576) { W = Wkv;  bptr = bkv;  ncol = 384; lc0 = u0 - 192; }
    else if (u0 < 720) { W = Wqp;  bptr = bqp;  ncol = 144; lc0 = u0 - 576; }
    else               { W = Wkvp; bptr = bkvp; ncol = 432; lc0 = u0 - 720; }

    float acc[4] = {0.f, 0.f, 0.f, 0.f};

    #pragma unroll 2
    for (int k = 0; k < CS; k += 4) {
        float4 w0 = *(const float4*)&W[(k + 0) * ncol + lc0];
        float4 w1 = *(const float4*)&W[(k + 1) * ncol + lc0];
        float4 w2 = *(const float4*)&W[(k + 2) * ncol + lc0];
        float4 w3 = *(const float4*)&W[(k + 3) * ncol + lc0];
        float4 sv = *(const float4*)&st[tr * CS + k];
        acc[0] += sv.x * w0.x + sv.y * w1.x + sv.z * w2.x + sv.w * w3.x;
        acc[1] += sv.x * w0.y + sv.y * w1.y + sv.z * w2.y + sv.w * w3.y;
        acc[2] += sv.x * w0.z + sv.y * w1.z + sv.z * w2.z + sv.w * w3.z;
        acc[3] += sv.x * w0.w + sv.y * w1.w + sv.z * w2.w + sv.w * w3.w;
    }

    const int n = n0 + tr;
    #pragma unroll
    for (int c = 0; c < 4; c++) {
        const int u = u0 + c;
        const float bias = bptr[lc0 + c];
        int oidx;
        if (u < 192) oidx = OFF_Q + n * 192 + u;
        else if (u < 576) {
            int lc = u - 192, h = lc >> 5, w = lc & 31;
            oidx = (w < 16) ? OFF_K + n * 192 + h * 16 + w
                            : OFF_V + n * 192 + h * 16 + (w - 16);
        } else if (u < 720) oidx = OFF_QRAW + n * 144 + (u - 576);
        else                oidx = OFF_KVRAW + n * 432 + (u - 720);
        ws[oidx] = acc[c] + bias;
    }
}

// ---------------- kernel 2: rigid transform of point projections (AoS VPTS) ----------------
__global__ __launch_bounds__(192) void point_kernel(
    const float* __restrict__ t_trans, const float* __restrict__ t_rots,
    float* __restrict__ ws)
{
    const int n = blockIdx.x;
    const int t = threadIdx.x;
    __shared__ float R[9], tr[3];
    if (t < 9) R[t] = t_rots[n * 9 + t];
    if (t < 3) tr[t] = t_trans[n * 3 + t];
    __syncthreads();

    float x0, x1, x2;
    int base;
    if (t < 48) {
        int idx = t;
        x0 = ws[OFF_QRAW + n * 144 + 0 * 48 + idx];
        x1 = ws[OFF_QRAW + n * 144 + 1 * 48 + idx];
        x2 = ws[OFF_QRAW + n * 144 + 2 * 48 + idx];
        int h = idx >> 2, p = idx & 3;
        base = OFF_QPTS + ((n * NH + h) * PQ + p) * 3;
    } else {                       // t = 48..191 -> idx 0..143 (ALL kv points)
        int idx = t - 48;
        x0 = ws[OFF_KVRAW + n * 432 + 0 * 144 + idx];
        x1 = ws[OFF_KVRAW + n * 432 + 1 * 144 + idx];
        x2 = ws[OFF_KVRAW + n * 432 + 2 * 144 + idx];
        int h = idx / 12, p = idx % 12;
        if (p < PQ) base = OFF_KPTS + ((n * NH + h) * PQ + p) * 3;
        else        base = OFF_VPTS + (n * NH * PV + h * PV + (p - PQ)) * 3;
    }
    ws[base + 0] = R[0] * x0 + R[1] * x1 + R[2] * x2 + tr[0];
    ws[base + 1] = R[3] * x0 + R[4] * x1 + R[5] * x2 + tr[1];
    ws[base + 2] = R[6] * x0 + R[7] * x1 + R[8] * x2 + tr[2];
}

// ---------------- kernel 3: A0 = cqk*qk - 0.5*hw*d2 + mask ----------------
__global__ __launch_bounds__(192) void logitA_kernel(
    const float* __restrict__ mask, const float* __restrict__ hweights,
    float* __restrict__ ws)
{
    const int j0 = blockIdx.x * 16;
    const int i0 = blockIdx.y * 16;
    const int t = threadIdx.x;

    __shared__ float qt[16 * 200];
    __shared__ float kt[16 * 200];
    __shared__ float qpt[16 * 148];
    __shared__ float kpt[16 * 148];
    __shared__ float mi[16], mj[16];

    {
        const float* src = ws + OFF_Q + i0 * 192;
        for (int idx = t * 4; idx < 3072; idx += 768) {
            float4 v = *(const float4*)&src[idx];
            *(float4*)&qt[(idx / 192) * 200 + idx % 192] = v;
        }
    }
    {
        const float* src = ws + OFF_K + j0 * 192;
        for (int idx = t * 4; idx < 3072; idx += 768) {
            float4 v = *(const float4*)&src[idx];
            *(float4*)&kt[(idx / 192) * 200 + idx % 192] = v;
        }
    }
    {
        const float* src = ws + OFF_QPTS + i0 * 144;
        for (int idx = t * 4; idx < 2304; idx += 768) {
            float4 v = *(const float4*)&src[idx];
            *(float4*)&qpt[(idx / 144) * 148 + idx % 144] = v;
        }
    }
    {
        const float* src = ws + OFF_KPTS + j0 * 144;
        for (int idx = t * 4; idx < 2304; idx += 768) {
            float4 v = *(const float4*)&src[idx];
            *(float4*)&kpt[(idx / 144) * 148 + idx % 144] = v;
        }
    }
    if (t < 16) { mi[t] = mask[i0 + t]; mj[t] = mask[j0 + t]; }
    __syncthreads();

    const int jj = t & 15;
    const int h = t >> 4;
    const float hw = log1pf(expf(hweights[h])) * 0.13608276348795434f;
    const float cqk = 0.14433756729740643f;

    float4 kr0 = *(const float4*)&kt[jj * 200 + h * 16 + 0];
    float4 kr1 = *(const float4*)&kt[jj * 200 + h * 16 + 4];
    float4 kr2 = *(const float4*)&kt[jj * 200 + h * 16 + 8];
    float4 kr3 = *(const float4*)&kt[jj * 200 + h * 16 + 12];
    float4 kp0 = *(const float4*)&kpt[jj * 148 + h * 12 + 0];
    float4 kp1 = *(const float4*)&kpt[jj * 148 + h * 12 + 4];
    float4 kp2 = *(const float4*)&kpt[jj * 148 + h * 12 + 8];
    const float mjv = mj[jj];

    for (int ii = 0; ii < 16; ii++) {
        float4 q0 = *(const float4*)&qt[ii * 200 + h * 16 + 0];
        float4 q1 = *(const float4*)&qt[ii * 200 + h * 16 + 4];
        float4 q2 = *(const float4*)&qt[ii * 200 + h * 16 + 8];
        float4 q3 = *(const float4*)&qt[ii * 200 + h * 16 + 12];
        float qk = q0.x * kr0.x + q0.y * kr0.y + q0.z * kr0.z + q0.w * kr0.w
                 + q1.x * kr1.x + q1.y * kr1.y + q1.z * kr1.z + q1.w * kr1.w
                 + q2.x * kr2.x + q2.y * kr2.y + q2.z * kr2.z + q2.w * kr2.w
                 + q3.x * kr3.x + q3.y * kr3.y + q3.z * kr3.z + q3.w * kr3.w;
        float4 p0 = *(const float4*)&qpt[ii * 148 + h * 12 + 0];
        float4 p1 = *(const float4*)&qpt[ii * 148 + h * 12 + 4];
        float4 p2 = *(const float4*)&qpt[ii * 148 + h * 12 + 8];
        float e, d2 = 0.f;
        e = p0.x - kp0.x; d2 += e * e;  e = p0.y - kp0.y; d2 += e * e;
        e = p0.z - kp0.z; d2 += e * e;  e = p0.w - kp0.w; d2 += e * e;
        e = p1.x - kp1.x; d2 += e * e;  e = p1.y - kp1.y; d2 += e * e;
        e = p1.z - kp1.z; d2 += e * e;  e = p1.w - kp1.w; d2 += e * e;
        e = p2.x - kp2.x; d2 += e * e;  e = p2.y - kp2.y; d2 += e * e;
        e = p2.z - kp2.z; d2 += e * e;  e = p2.w - kp2.w; d2 += e * e;
        float sm = 100000.0f * (mi[ii] * mjv - 1.0f);
        ws[OFF_A + ((size_t)(i0 + ii) * NH + h) * N + j0 + jj] =
            qk * cqk - 0.5f * hw * d2 + sm;
    }
}

// ---------------- kernel 4: b = z@Wb fused with +A0 and softmax ----------------
// Thread = (ch c-half, jj2 row-pair, hg head-triple): 2 rows x half-c each,
// partial-b reduced via shfl_xor(1). ch-duplication handled with inv = 2/sum.
__global__ __launch_bounds__(512) void bsoft_kernel(
    const float* __restrict__ z, const float* __restrict__ Wb,
    const float* __restrict__ bb, float* __restrict__ ws)
{
    const int i = blockIdx.x;
    const int t = threadIdx.x;
    __shared__ float zt[128 * 132];   // 67.6 KB
    __shared__ float wbt[12 * 132];   // Wb transposed [h][c]
    __shared__ float wred[8][4];      // per-wave softmax partials

    for (int idx = t; idx < CZ * NH; idx += 512) {
        int c = idx / NH, h = idx % NH;
        wbt[h * 132 + c] = Wb[idx];
    }

    const int ch  = t & 1;            // c-half 0/1
    const int jj2 = (t >> 1) & 63;    // rows jj2, jj2+64
    const int hg  = t >> 7;           // 0..3
    const int h0  = hg * 3;
    const float bb0 = bb[h0], bb1 = bb[h0 + 1], bb2 = bb[h0 + 2];
    const float cb = 0.5773502691896258f;

    float lg[3][2][4];

    for (int T = 0; T < 4; T++) {
        __syncthreads();
        const float* zsrc = z + ((size_t)i * N + T * 128) * CZ;
        for (int idx = t * 4; idx < 16384; idx += 2048) {
            float4 v = *(const float4*)&zsrc[idx];
            *(float4*)&zt[(idx >> 7) * 132 + (idx & 127)] = v;
        }
        __syncthreads();

        float a00 = 0.f, a01 = 0.f, a02 = 0.f;   // row jj2, heads h0..h0+2
        float a10 = 0.f, a11 = 0.f, a12 = 0.f;   // row jj2+64
        const float* zr0 = &zt[jj2 * 132 + ch * 64];
        const float* zr1 = &zt[(jj2 + 64) * 132 + ch * 64];
        const float* w0 = &wbt[(h0 + 0) * 132 + ch * 64];
        const float* w1 = &wbt[(h0 + 1) * 132 + ch * 64];
        const float* w2 = &wbt[(h0 + 2) * 132 + ch * 64];
        #pragma unroll
        for (int c = 0; c < 64; c += 4) {
            float4 zq0 = *(const float4*)&zr0[c];
            float4 zq1 = *(const float4*)&zr1[c];
            float4 q0 = *(const float4*)&w0[c];
            float4 q1 = *(const float4*)&w1[c];
            float4 q2 = *(const float4*)&w2[c];
            a00 += zq0.x * q0.x + zq0.y * q0.y + zq0.z * q0.z + zq0.w * q0.w;
            a01 += zq0.x * q1.x + zq0.y * q1.y + zq0.z * q1.z + zq0.w * q1.w;
            a02 += zq0.x * q2.x + zq0.y * q2.y + zq0.z * q2.z + zq0.w * q2.w;
            a10 += zq1.x * q0.x + zq1.y * q0.y + zq1.z * q0.z + zq1.w * q0.w;
            a11 += zq1.x * q1.x + zq1.y * q1.y + zq1.z * q1.z + zq1.w * q1.w;
            a12 += zq1.x * q2.x + zq1.y * q2.y + zq1.z * q2.z + zq1.w * q2.w;
        }
        // combine c-halves (lane pair ch=0/1)
        a00 += __shfl_xor(a00, 1); a01 += __shfl_xor(a01, 1); a02 += __shfl_xor(a02, 1);
        a10 += __shfl_xor(a10, 1); a11 += __shfl_xor(a11, 1); a12 += __shfl_xor(a12, 1);

        const float* arow = ws + OFF_A + (size_t)i * NH * N + T * 128;
        lg[0][0][T] = arow[(size_t)(h0 + 0) * N + jj2]      + cb * (a00 + bb0);
        lg[0][1][T] = arow[(size_t)(h0 + 0) * N + jj2 + 64] + cb * (a10 + bb0);
        lg[1][0][T] = arow[(size_t)(h0 + 1) * N + jj2]      + cb * (a01 + bb1);
        lg[1][1][T] = arow[(size_t)(h0 + 1) * N + jj2 + 64] + cb * (a11 + bb1);
        lg[2][0][T] = arow[(size_t)(h0 + 2) * N + jj2]      + cb * (a02 + bb2);
        lg[2][1][T] = arow[(size_t)(h0 + 2) * N + jj2 + 64] + cb * (a12 + bb2);
    }

    // softmax over j: each (i,h) row's 512 logits live (duplicated x2 by ch)
    // across the 128 threads of the hg group (2 waves).
    const int wv = t >> 6;
    float mx[3], sm[3];
    #pragma unroll
    for (int r = 0; r < 3; r++) {
        float m = -1e30f;
        #pragma unroll
        for (int rb = 0; rb < 2; rb++)
            #pragma unroll
            for (int T = 0; T < 4; T++) m = fmaxf(m, lg[r][rb][T]);
        #pragma unroll
        for (int o = 32; o > 0; o >>= 1) m = fmaxf(m, __shfl_xor(m, o));
        mx[r] = m;
    }
    if ((t & 63) == 0) {
        wred[wv][0] = mx[0]; wred[wv][1] = mx[1]; wred[wv][2] = mx[2];
    }
    __syncthreads();
    #pragma unroll
    for (int r = 0; r < 3; r++)
        mx[r] = fmaxf(wred[hg * 2][r], wred[hg * 2 + 1][r]);
    __syncthreads();   // protect wred reuse
    #pragma unroll
    for (int r = 0; r < 3; r++) {
        float s = 0.f;
        #pragma unroll
        for (int rb = 0; rb < 2; rb++)
            #pragma unroll
            for (int T = 0; T < 4; T++) {
                lg[r][rb][T] = __expf(lg[r][rb][T] - mx[r]);
                s += lg[r][rb][T];
            }
        #pragma unroll
        for (int o = 32; o > 0; o >>= 1) s += __shfl_xor(s, o);
        sm[r] = s;
    }
    if ((t & 63) == 0) {
        wred[wv][0] = sm[0]; wred[wv][1] = sm[1]; wred[wv][2] = sm[2];
    }
    __syncthreads();
    #pragma unroll
    for (int r = 0; r < 3; r++) {
        // each j counted twice (ch duplication) -> inv = 2/sum
        float inv = 2.0f / (wred[hg * 2][r] + wred[hg * 2 + 1][r]);
        float* prow = ws + OFF_A + ((size_t)i * NH + h0 + r) * N;
        #pragma unroll
        for (int T = 2 * ch; T < 2 * ch + 2; T++) {   // ch partitions the T-writes
            prow[T * 128 + jj2]      = lg[r][0][T] * inv;
            prow[T * 128 + jj2 + 64] = lg[r][1][T] * inv;
        }
    }
}

// ---------------- kernel 5: o / o_pt / o_pair — 2-way j-split, deep load pipeline ----------------
__global__ __launch_bounds__(960) void finish_kernel(
    const float* __restrict__ z, const float* __restrict__ t_trans,
    const float* __restrict__ t_rots, const float* __restrict__ ws_c,
    float* __restrict__ ws)
{
    const int i = blockIdx.x;
    const int t = threadIdx.x;
    __shared__ float a_s[12 * 520];        // 24.96 KB
    __shared__ float pr_pair[192 * 8];     // 6 KB partials
    __shared__ float pr_o[192];
    __shared__ float pr_pt[96 * 3];

    {
        const float* src = ws_c + OFF_A + (size_t)i * (NH * N);
        for (int idx = t * 4; idx < NH * N; idx += 960 * 4) {
            float4 v = *(const float4*)&src[idx];
            int h = idx >> 9, j = idx & 511;
            *(float4*)&a_s[h * 520 + j] = v;
        }
    }
    __syncthreads();

    float* cat = ws + OFF_CAT + (size_t)i * 2112;

    float4 accA = {0,0,0,0}, accB = {0,0,0,0};   // o_pair
    float accO = 0.f;                            // o
    float g0 = 0.f, g1 = 0.f, g2 = 0.f;          // o_pt

    int jh = 0, v = 0;

    if (t < 384) {          // o_pair — 8 j per iter, all loads issued first
        jh = (t >= 192); v = t - jh * 192;
        const int cg = v & 31;
        const int hs = v >> 5;
        const float* zb = z + (size_t)i * N * CZ + cg * 4;
        const float* ahA = a_s + hs * 520;
        const float* ahB = a_s + (hs + 6) * 520;
        const int j0 = jh * 256;
        for (int jo = 0; jo < 256; jo += 8) {
            const int j = j0 + jo;
            float4 z0 = *(const float4*)&zb[(size_t)(j + 0) * CZ];
            float4 z1 = *(const float4*)&zb[(size_t)(j + 1) * CZ];
            float4 z2 = *(const float4*)&zb[(size_t)(j + 2) * CZ];
            float4 z3 = *(const float4*)&zb[(size_t)(j + 3) * CZ];
            float4 z4 = *(const float4*)&zb[(size_t)(j + 4) * CZ];
            float4 z5 = *(const float4*)&zb[(size_t)(j + 5) * CZ];
            float4 z6 = *(const float4*)&zb[(size_t)(j + 6) * CZ];
            float4 z7 = *(const float4*)&zb[(size_t)(j + 7) * CZ];
            float4 aA0 = *(const float4*)&ahA[j];
            float4 aA1 = *(const float4*)&ahA[j + 4];
            float4 aB0 = *(const float4*)&ahB[j];
            float4 aB1 = *(const float4*)&ahB[j + 4];
            accA.x += aA0.x * z0.x + aA0.y * z1.x + aA0.z * z2.x + aA0.w * z3.x
                    + aA1.x * z4.x + aA1.y * z5.x + aA1.z * z6.x + aA1.w * z7.x;
            accA.y += aA0.x * z0.y + aA0.y * z1.y + aA0.z * z2.y + aA0.w * z3.y
                    + aA1.x * z4.y + aA1.y * z5.y + aA1.z * z6.y + aA1.w * z7.y;
            accA.z += aA0.x * z0.z + aA0.y * z1.z + aA0.z * z2.z + aA0.w * z3.z
                    + aA1.x * z4.z + aA1.y * z5.z + aA1.z * z6.z + aA1.w * z7.z;
            accA.w += aA0.x * z0.w + aA0.y * z1.w + aA0.z * z2.w + aA0.w * z3.w
                    + aA1.x * z4.w + aA1.y * z5.w + aA1.z * z6.w + aA1.w * z7.w;
            accB.x += aB0.x * z0.x + aB0.y * z1.x + aB0.z * z2.x + aB0.w * z3.x
                    + aB1.x * z4.x + aB1.y * z5.x + aB1.z * z6.x + aB1.w * z7.x;
            accB.y += aB0.x * z0.y + aB0.y * z1.y + aB0.z * z2.y + aB0.w * z3.y
                    + aB1.x * z4.y + aB1.y * z5.y + aB1.z * z6.y + aB1.w * z7.y;
            accB.z += aB0.x * z0.z + aB0.y * z1.z + aB0.z * z2.z + aB0.w * z3.z
                    + aB1.x * z4.z + aB1.y * z5.z + aB1.z * z6.z + aB1.w * z7.z;
            accB.w += aB0.x * z0.w + aB0.y * z1.w + aB0.z * z2.w + aB0.w * z3.w
                    + aB1.x * z4.w + aB1.y * z5.w + aB1.z * z6.w + aB1.w * z7.w;
        }
    } else if (t < 768) {   // o — 8 scalar v loads in flight
        const int u = t - 384;
        jh = (u >= 192); v = u - jh * 192;
        const int h = v >> 4, cc = v & 15;
        const float* vcol = ws_c + OFF_V + h * 16 + cc;
        const float* ah = a_s + h * 520;
        const int j0 = jh * 256;
        for (int jo = 0; jo < 256; jo += 8) {
            const int j = j0 + jo;
            float v0 = vcol[(j + 0) * 192];
            float v1 = vcol[(j + 1) * 192];
            float v2 = vcol[(j + 2) * 192];
            float v3 = vcol[(j + 3) * 192];
            float v4 = vcol[(j + 4) * 192];
            float v5 = vcol[(j + 5) * 192];
            float v6 = vcol[(j + 6) * 192];
            float v7 = vcol[(j + 7) * 192];
            float4 a0 = *(const float4*)&ah[j];
            float4 a1 = *(const float4*)&ah[j + 4];
            accO += a0.x * v0 + a0.y * v1 + a0.z * v2 + a0.w * v3
                  + a1.x * v4 + a1.y * v5 + a1.z * v6 + a1.w * v7;
        }
    } else {                // o_pt (AoS) — 12 scalar loads in flight per 4 j
        const int u = t - 768;
        jh = (u >= 96); v = u - jh * 96;
        const int h = v >> 3, p = v & 7;
        const float* vp = ws_c + OFF_VPTS + (h * PV + p) * 3;
        const float* ah = a_s + h * 520;
        const int j0 = jh * 256;
        for (int jo = 0; jo < 256; jo += 4) {
            const int j = j0 + jo;
            const float* p0 = vp + (size_t)(j + 0) * 288;
            const float* p1 = vp + (size_t)(j + 1) * 288;
            const float* p2 = vp + (size_t)(j + 2) * 288;
            const float* p3 = vp + (size_t)(j + 3) * 288;
            float x0 = p0[0], y0 = p0[1], w0 = p0[2];
            float x1 = p1[0], y1 = p1[1], w1 = p1[2];
            float x2 = p2[0], y2 = p2[1], w2 = p2[2];
            float x3 = p3[0], y3 = p3[1], w3 = p3[2];
            float4 a4 = *(const float4*)&ah[j];
            g0 += a4.x * x0 + a4.y * x1 + a4.z * x2 + a4.w * x3;
            g1 += a4.x * y0 + a4.y * y1 + a4.z * y2 + a4.w * y3;
            g2 += a4.x * w0 + a4.y * w1 + a4.z * w2 + a4.w * w3;
        }
    }

    // half-1 publishes partials
    if (jh == 1) {
        if (t < 384) {
            float* d = pr_pair + v * 8;
            d[0] = accA.x; d[1] = accA.y; d[2] = accA.z; d[3] = accA.w;
            d[4] = accB.x; d[5] = accB.y; d[6] = accB.z; d[7] = accB.w;
        } else if (t < 768) {
            pr_o[v] = accO;
        } else {
            pr_pt[v * 3 + 0] = g0; pr_pt[v * 3 + 1] = g1; pr_pt[v * 3 + 2] = g2;
        }
    }
    __syncthreads();

    // half-0 combines + epilogue
    if (jh == 0) {
        if (t < 384) {
            const float* d = pr_pair + v * 8;
            accA.x += d[0]; accA.y += d[1]; accA.z += d[2]; accA.w += d[3];
            accB.x += d[4]; accB.y += d[5]; accB.z += d[6]; accB.w += d[7];
            const int cg = v & 31, hs = v >> 5;
            *(float4*)&cat[576 + hs * CZ + cg * 4]       = accA;
            *(float4*)&cat[576 + (hs + 6) * CZ + cg * 4] = accB;
        } else if (t < 768) {
            accO += pr_o[v];
            const int h = v >> 4, cc = v & 15;
            cat[h * 16 + cc] = accO;
        } else {
            g0 += pr_pt[v * 3 + 0]; g1 += pr_pt[v * 3 + 1]; g2 += pr_pt[v * 3 + 2];
            float R[9], ti[3];
            #pragma unroll
            for (int x = 0; x < 9; x++) R[x] = t_rots[i * 9 + x];
            #pragma unroll
            for (int x = 0; x < 3; x++) ti[x] = t_trans[i * 3 + x];
            g0 -= ti[0]; g1 -= ti[1]; g2 -= ti[2];
            float l0 = R[0] * g0 + R[3] * g1 + R[6] * g2;
            float l1 = R[1] * g0 + R[4] * g1 + R[7] * g2;
            float l2 = R[2] * g0 + R[5] * g1 + R[8] * g2;
            float nrm = sqrtf(l0 * l0 + l1 * l1 + l2 * l2 + 1e-8f);
            const int h = v >> 3, p = v & 7;
            int e = h * PV + p;
            cat[192 + e] = l0;
            cat[288 + e] = l1;
            cat[384 + e] = l2;
            cat[480 + e] = nrm;
        }
    }
}

// ---------------- kernel 6: out partials = cat @ Wout k-chunk (no atomics) ----------------
__global__ __launch_bounds__(384, 4) void out_kernel(
    const float* __restrict__ Wout, const float* __restrict__ ws_c,
    float* __restrict__ ws)
{
    const int rt = blockIdx.x;
    const int kc = blockIdx.y;
    const int t = threadIdx.x;
    __shared__ float ct[16 * 132];
    for (int idx = t * 4; idx < 16 * 132; idx += 384 * 4) {
        int rr = idx / 132, kk = idx % 132;
        *(float4*)&ct[idx] =
            *(const float4*)&ws_c[OFF_CAT + (size_t)(rt * 16 + rr) * 2112 + kc * 132 + kk];
    }
    __syncthreads();
    const int cq = t % 96, rg = t / 96;
    const int c0 = cq * 4;
    float acc[4][4] = {};
    const float* Wp = Wout + (size_t)kc * 132 * 384 + c0;
    #pragma unroll 4
    for (int kk = 0; kk < 132; kk += 4) {
        float4 w0 = *(const float4*)&Wp[(size_t)(kk + 0) * 384];
        float4 w1 = *(const float4*)&Wp[(size_t)(kk + 1) * 384];
        float4 w2 = *(const float4*)&Wp[(size_t)(kk + 2) * 384];
        float4 w3 = *(const float4*)&Wp[(size_t)(kk + 3) * 384];
        #pragma unroll
        for (int r = 0; r < 4; r++) {
            float4 sv = *(const float4*)&ct[(rg * 4 + r) * 132 + kk];
            acc[r][0] += sv.x * w0.x + sv.y * w1.x + sv.z * w2.x + sv.w * w3.x;
            acc[r][1] += sv.x * w0.y + sv.y * w1.y + sv.z * w2.y + sv.w * w3.y;
            acc[r][2] += sv.x * w0.z + sv.y * w1.z + sv.z * w2.z + sv.w * w3.z;
            acc[r][3] += sv.x * w0.w + sv.y * w1.w + sv.z * w2.w + sv.w * w3.w;
        }
    }
    float* dst = ws + OFF_A + (size_t)kc * (512 * 384);
    #pragma unroll
    for (int r = 0; r < 4; r++) {
        float4 a4 = make_float4(acc[r][0], acc[r][1], acc[r][2], acc[r][3]);
        *(float4*)&dst[(size_t)(rt * 16 + rg * 4 + r) * 384 + c0] = a4;
    }
}

// ---------------- kernel 7: out = bias + sum of 16 partials ----------------
__global__ __launch_bounds__(256) void reduce_out_kernel(
    const float* __restrict__ bout, const float* __restrict__ ws,
    float* __restrict__ out)
{
    const int idx = (blockIdx.x * 256 + threadIdx.x) * 4;   // float offset, < 512*384
    const int col = idx % 384;
    float4 acc = *(const float4*)&bout[col];
    #pragma unroll
    for (int kc = 0; kc < 16; kc++) {
        float4 p = *(const float4*)&ws[OFF_A + (size_t)kc * (512 * 384) + idx];
        acc.x += p.x; acc.y += p.y; acc.z += p.z; acc.w += p.w;
    }
    *(float4*)&out[idx] = acc;
}

extern "C" void kernel_launch(void* const* d_in, const int* in_sizes, int n_in,
                              void* d_out, int out_size, void* d_ws, size_t ws_size,
                              hipStream_t stream) {
    const float* s       = (const float*)d_in[0];
    const float* z       = (const float*)d_in[1];
    const float* t_trans = (const float*)d_in[2];
    const float* t_rots  = (const float*)d_in[3];
    const float* mask    = (const float*)d_in[4];
    const float* Wq      = (const float*)d_in[5];
    const float* bq      = (const float*)d_in[6];
    const float* Wkv     = (const float*)d_in[7];
    const float* bkv     = (const float*)d_in[8];
    const float* Wqp     = (const float*)d_in[9];
    const float* bqp     = (const float*)d_in[10];
    const float* Wkvp    = (const float*)d_in[11];
    const float* bkvp    = (const float*)d_in[12];
    const float* Wb      = (const float*)d_in[13];
    const float* bb      = (const float*)d_in[14];
    const float* hweights= (const float*)d_in[15];
    const float* Wout    = (const float*)d_in[16];
    const float* bout    = (const float*)d_in[17];
    float* ws  = (float*)d_ws;
    float* out = (float*)d_out;

    proj_kernel<<<dim3(32, 18), 256, 0, stream>>>(s, Wq, bq, Wkv, bkv, Wqp, bqp, Wkvp, bkvp, ws);
    point_kernel<<<512, 192, 0, stream>>>(t_trans, t_rots, ws);
    logitA_kernel<<<dim3(32, 32), 192, 0, stream>>>(mask, hweights, ws);
    bsoft_kernel<<<512, 512, 0, stream>>>(z, Wb, bb, ws);
    finish_kernel<<<512, 960, 0, stream>>>(z, t_trans, t_rots, ws, ws);
    out_kernel<<<dim3(32, 16), 384, 0, stream>>>(Wout, ws, ws);
    reduce_out_kernel<<<192, 256, 0, stream>>>(bout, ws, out);
}

// Round 9
// 374.807 us; speedup vs baseline: 1.0590x; 1.0590x over previous
//
#include <hip/hip_runtime.h>
#include <math.h>

#define N 512
#define CS 384
#define CZ 128
#define CH 16
#define NH 12
#define PQ 4
#define PV 8

// workspace layout (float offsets)
#define OFF_Q     0          // 512*192
#define OFF_K     98304      // 512*192
#define OFF_V     196608     // 512*192
#define OFF_QRAW  294912     // 512*144
#define OFF_KVRAW 368640     // 512*432
#define OFF_QPTS  589824     // 512*144
#define OFF_KPTS  663552     // 512*144
#define OFF_VPTS  737280     // 512*288 AoS: [n][h*PV+p][xyz]
#define OFF_A     884736     // 512*12*512 = 3145728  (A0 logits -> probs -> out partials)
#define OFF_CAT   4030464    // 512*2112
// end = 5111808 floats

// ---------------- kernel 1: fused projections, 64-col tiles for 2x blocks ----------------
__global__ __launch_bounds__(256) void proj_kernel(
    const float* __restrict__ s,
    const float* __restrict__ Wq,  const float* __restrict__ bq,
    const float* __restrict__ Wkv, const float* __restrict__ bkv,
    const float* __restrict__ Wqp, const float* __restrict__ bqp,
    const float* __restrict__ Wkvp,const float* __restrict__ bkvp,
    float* __restrict__ ws)
{
    __shared__ float st[16 * CS];   // 24 KB
    const int n0 = blockIdx.x * 16;
    for (int idx = threadIdx.x * 4; idx < 16 * CS; idx += 256 * 4)
        *(float4*)&st[idx] = *(const float4*)&s[n0 * CS + idx];
    __syncthreads();

    const int tc = threadIdx.x & 15;       // 16 col-quads -> 64 cols
    const int tr = threadIdx.x >> 4;       // 16 rows, 1 row/thread
    const int u0 = blockIdx.y * 64 + tc * 4;

    const float* W; const float* bptr; int ncol, lc0;
    if (u0 < 192)      { W = Wq;   bptr = bq;   ncol = 192; lc0 = u0; }
    else if (u0 < 576) { W = Wkv;  bptr = bkv;  ncol = 384; lc0 = u0 - 192; }
    else if (u0 < 720) { W = Wqp;  bptr = bqp;  ncol = 144; lc0 = u0 - 576; }
    else               { W = Wkvp; bptr = bkvp; ncol = 432; lc0 = u0 - 720; }

    float acc[4] = {0.f, 0.f, 0.f, 0.f};

    #pragma unroll 2
    for (int k = 0; k < CS; k += 4) {
        float4 w0 = *(const float4*)&W[(k + 0) * ncol + lc0];
        float4 w1 = *(const float4*)&W[(k + 1) * ncol + lc0];
        float4 w2 = *(const float4*)&W[(k + 2) * ncol + lc0];
        float4 w3 = *(const float4*)&W[(k + 3) * ncol + lc0];
        float4 sv = *(const float4*)&st[tr * CS + k];
        acc[0] += sv.x * w0.x + sv.y * w1.x + sv.z * w2.x + sv.w * w3.x;
        acc[1] += sv.x * w0.y + sv.y * w1.y + sv.z * w2.y + sv.w * w3.y;
        acc[2] += sv.x * w0.z + sv.y * w1.z + sv.z * w2.z + sv.w * w3.z;
        acc[3] += sv.x * w0.w + sv.y * w1.w + sv.z * w2.w + sv.w * w3.w;
    }

    const int n = n0 + tr;
    #pragma unroll
    for (int c = 0; c < 4; c++) {
        const int u = u0 + c;
        const float bias = bptr[lc0 + c];
        int oidx;
        if (u < 192) oidx = OFF_Q + n * 192 + u;
        else if (u < 576) {
            int lc = u - 192, h = lc >> 5, w = lc & 31;
            oidx = (w < 16) ? OFF_K + n * 192 + h * 16 + w
                            : OFF_V + n * 192 + h * 16 + (w - 16);
        } else if (u < 720) oidx = OFF_QRAW + n * 144 + (u - 576);
        else                oidx = OFF_KVRAW + n * 432 + (u - 720);
        ws[oidx] = acc[c] + bias;
    }
}

// ---------------- kernel 2: rigid transform of point projections (AoS VPTS) ----------------
__global__ __launch_bounds__(192) void point_kernel(
    const float* __restrict__ t_trans, const float* __restrict__ t_rots,
    float* __restrict__ ws)
{
    const int n = blockIdx.x;
    const int t = threadIdx.x;
    __shared__ float R[9], tr[3];
    if (t < 9) R[t] = t_rots[n * 9 + t];
    if (t < 3) tr[t] = t_trans[n * 3 + t];
    __syncthreads();

    float x0, x1, x2;
    int base;
    if (t < 48) {
        int idx = t;
        x0 = ws[OFF_QRAW + n * 144 + 0 * 48 + idx];
        x1 = ws[OFF_QRAW + n * 144 + 1 * 48 + idx];
        x2 = ws[OFF_QRAW + n * 144 + 2 * 48 + idx];
        int h = idx >> 2, p = idx & 3;
        base = OFF_QPTS + ((n * NH + h) * PQ + p) * 3;
    } else {                       // t = 48..191 -> idx 0..143 (ALL kv points)
        int idx = t - 48;
        x0 = ws[OFF_KVRAW + n * 432 + 0 * 144 + idx];
        x1 = ws[OFF_KVRAW + n * 432 + 1 * 144 + idx];
        x2 = ws[OFF_KVRAW + n * 432 + 2 * 144 + idx];
        int h = idx / 12, p = idx % 12;
        if (p < PQ) base = OFF_KPTS + ((n * NH + h) * PQ + p) * 3;
        else        base = OFF_VPTS + (n * NH * PV + h * PV + (p - PQ)) * 3;
    }
    ws[base + 0] = R[0] * x0 + R[1] * x1 + R[2] * x2 + tr[0];
    ws[base + 1] = R[3] * x0 + R[4] * x1 + R[5] * x2 + tr[1];
    ws[base + 2] = R[6] * x0 + R[7] * x1 + R[8] * x2 + tr[2];
}

// ---------------- kernel 3: A0 = cqk*qk - 0.5*hw*d2 + mask ----------------
__global__ __launch_bounds__(192) void logitA_kernel(
    const float* __restrict__ mask, const float* __restrict__ hweights,
    float* __restrict__ ws)
{
    const int j0 = blockIdx.x * 16;
    const int i0 = blockIdx.y * 16;
    const int t = threadIdx.x;

    __shared__ float qt[16 * 200];
    __shared__ float kt[16 * 200];
    __shared__ float qpt[16 * 148];
    __shared__ float kpt[16 * 148];
    __shared__ float mi[16], mj[16];

    {
        const float* src = ws + OFF_Q + i0 * 192;
        for (int idx = t * 4; idx < 3072; idx += 768) {
            float4 v = *(const float4*)&src[idx];
            *(float4*)&qt[(idx / 192) * 200 + idx % 192] = v;
        }
    }
    {
        const float* src = ws + OFF_K + j0 * 192;
        for (int idx = t * 4; idx < 3072; idx += 768) {
            float4 v = *(const float4*)&src[idx];
            *(float4*)&kt[(idx / 192) * 200 + idx % 192] = v;
        }
    }
    {
        const float* src = ws + OFF_QPTS + i0 * 144;
        for (int idx = t * 4; idx < 2304; idx += 768) {
            float4 v = *(const float4*)&src[idx];
            *(float4*)&qpt[(idx / 144) * 148 + idx % 144] = v;
        }
    }
    {
        const float* src = ws + OFF_KPTS + j0 * 144;
        for (int idx = t * 4; idx < 2304; idx += 768) {
            float4 v = *(const float4*)&src[idx];
            *(float4*)&kpt[(idx / 144) * 148 + idx % 144] = v;
        }
    }
    if (t < 16) { mi[t] = mask[i0 + t]; mj[t] = mask[j0 + t]; }
    __syncthreads();

    const int jj = t & 15;
    const int h = t >> 4;
    const float hw = log1pf(expf(hweights[h])) * 0.13608276348795434f;
    const float cqk = 0.14433756729740643f;

    float4 kr0 = *(const float4*)&kt[jj * 200 + h * 16 + 0];
    float4 kr1 = *(const float4*)&kt[jj * 200 + h * 16 + 4];
    float4 kr2 = *(const float4*)&kt[jj * 200 + h * 16 + 8];
    float4 kr3 = *(const float4*)&kt[jj * 200 + h * 16 + 12];
    float4 kp0 = *(const float4*)&kpt[jj * 148 + h * 12 + 0];
    float4 kp1 = *(const float4*)&kpt[jj * 148 + h * 12 + 4];
    float4 kp2 = *(const float4*)&kpt[jj * 148 + h * 12 + 8];
    const float mjv = mj[jj];

    for (int ii = 0; ii < 16; ii++) {
        float4 q0 = *(const float4*)&qt[ii * 200 + h * 16 + 0];
        float4 q1 = *(const float4*)&qt[ii * 200 + h * 16 + 4];
        float4 q2 = *(const float4*)&qt[ii * 200 + h * 16 + 8];
        float4 q3 = *(const float4*)&qt[ii * 200 + h * 16 + 12];
        float qk = q0.x * kr0.x + q0.y * kr0.y + q0.z * kr0.z + q0.w * kr0.w
                 + q1.x * kr1.x + q1.y * kr1.y + q1.z * kr1.z + q1.w * kr1.w
                 + q2.x * kr2.x + q2.y * kr2.y + q2.z * kr2.z + q2.w * kr2.w
                 + q3.x * kr3.x + q3.y * kr3.y + q3.z * kr3.z + q3.w * kr3.w;
        float4 p0 = *(const float4*)&qpt[ii * 148 + h * 12 + 0];
        float4 p1 = *(const float4*)&qpt[ii * 148 + h * 12 + 4];
        float4 p2 = *(const float4*)&qpt[ii * 148 + h * 12 + 8];
        float e, d2 = 0.f;
        e = p0.x - kp0.x; d2 += e * e;  e = p0.y - kp0.y; d2 += e * e;
        e = p0.z - kp0.z; d2 += e * e;  e = p0.w - kp0.w; d2 += e * e;
        e = p1.x - kp1.x; d2 += e * e;  e = p1.y - kp1.y; d2 += e * e;
        e = p1.z - kp1.z; d2 += e * e;  e = p1.w - kp1.w; d2 += e * e;
        e = p2.x - kp2.x; d2 += e * e;  e = p2.y - kp2.y; d2 += e * e;
        e = p2.z - kp2.z; d2 += e * e;  e = p2.w - kp2.w; d2 += e * e;
        float sm = 100000.0f * (mi[ii] * mjv - 1.0f);
        ws[OFF_A + ((size_t)(i0 + ii) * NH + h) * N + j0 + jj] =
            qk * cqk - 0.5f * hw * d2 + sm;
    }
}

// ---------------- kernel 4: b = z@Wb fused with +A0 and softmax (one block per i) ----------------
// wbt-LDS version: row-read pattern jj = t&127, stride 132 -> zero bank conflicts.
__global__ __launch_bounds__(512) void bsoft_kernel(
    const float* __restrict__ z, const float* __restrict__ Wb,
    const float* __restrict__ bb, float* __restrict__ ws)
{
    const int i = blockIdx.x;
    const int t = threadIdx.x;
    __shared__ float zt[128 * 132];   // 67.6 KB, stride 132 -> conflict-free b128 rows
    __shared__ float wbt[12 * 132];   // Wb transposed [h][c]
    __shared__ float wred[8][4];      // per-wave softmax partials

    for (int idx = t; idx < CZ * NH; idx += 512) {
        int c = idx / NH, h = idx % NH;
        wbt[h * 132 + c] = Wb[idx];
    }

    const int jj = t & 127;
    const int hg = t >> 7;      // 0..3
    const int h0 = hg * 3;
    const float bb0 = bb[h0], bb1 = bb[h0 + 1], bb2 = bb[h0 + 2];
    const float cb = 0.5773502691896258f;

    float lg[3][4];

    for (int T = 0; T < 4; T++) {
        __syncthreads();
        const float* zsrc = z + ((size_t)i * N + T * 128) * CZ;
        for (int idx = t * 4; idx < 16384; idx += 2048) {
            float4 v = *(const float4*)&zsrc[idx];
            *(float4*)&zt[(idx >> 7) * 132 + (idx & 127)] = v;
        }
        __syncthreads();

        float a0 = bb0, a1 = bb1, a2 = bb2;
        const float* zr = &zt[jj * 132];
        const float* w0 = &wbt[(h0 + 0) * 132];
        const float* w1 = &wbt[(h0 + 1) * 132];
        const float* w2 = &wbt[(h0 + 2) * 132];
        #pragma unroll
        for (int c = 0; c < CZ; c += 4) {
            float4 zq = *(const float4*)&zr[c];
            float4 q0 = *(const float4*)&w0[c];
            float4 q1 = *(const float4*)&w1[c];
            float4 q2 = *(const float4*)&w2[c];
            a0 += zq.x * q0.x + zq.y * q0.y + zq.z * q0.z + zq.w * q0.w;
            a1 += zq.x * q1.x + zq.y * q1.y + zq.z * q1.z + zq.w * q1.w;
            a2 += zq.x * q2.x + zq.y * q2.y + zq.z * q2.z + zq.w * q2.w;
        }
        const float* arow = ws + OFF_A + (size_t)i * NH * N + T * 128 + jj;
        lg[0][T] = arow[(size_t)(h0 + 0) * N] + cb * a0;
        lg[1][T] = arow[(size_t)(h0 + 1) * N] + cb * a1;
        lg[2][T] = arow[(size_t)(h0 + 2) * N] + cb * a2;
    }

    const int wv = t >> 6;
    float mx[3], sm[3];
    #pragma unroll
    for (int r = 0; r < 3; r++) {
        float m = fmaxf(fmaxf(lg[r][0], lg[r][1]), fmaxf(lg[r][2], lg[r][3]));
        #pragma unroll
        for (int o = 32; o > 0; o >>= 1) m = fmaxf(m, __shfl_xor(m, o));
        mx[r] = m;
    }
    if ((t & 63) == 0) {
        wred[wv][0] = mx[0]; wred[wv][1] = mx[1]; wred[wv][2] = mx[2];
    }
    __syncthreads();
    #pragma unroll
    for (int r = 0; r < 3; r++)
        mx[r] = fmaxf(wred[hg * 2][r], wred[hg * 2 + 1][r]);
    __syncthreads();   // protect wred reuse
    #pragma unroll
    for (int r = 0; r < 3; r++) {
        float s = 0.f;
        #pragma unroll
        for (int T = 0; T < 4; T++) { lg[r][T] = __expf(lg[r][T] - mx[r]); s += lg[r][T]; }
        #pragma unroll
        for (int o = 32; o > 0; o >>= 1) s += __shfl_xor(s, o);
        sm[r] = s;
    }
    if ((t & 63) == 0) {
        wred[wv][0] = sm[0]; wred[wv][1] = sm[1]; wred[wv][2] = sm[2];
    }
    __syncthreads();
    #pragma unroll
    for (int r = 0; r < 3; r++) {
        float inv = 1.0f / (wred[hg * 2][r] + wred[hg * 2 + 1][r]);
        float* prow = ws + OFF_A + ((size_t)i * NH + h0 + r) * N + jj;
        #pragma unroll
        for (int T = 0; T < 4; T++)
            prow[T * 128] = lg[r][T] * inv;
    }
}

// ---------------- kernel 5: o / o_pt / o_pair — 2-way j-split, deep load pipeline ----------------
__global__ __launch_bounds__(960) void finish_kernel(
    const float* __restrict__ z, const float* __restrict__ t_trans,
    const float* __restrict__ t_rots, const float* __restrict__ ws_c,
    float* __restrict__ ws)
{
    const int i = blockIdx.x;
    const int t = threadIdx.x;
    __shared__ float a_s[12 * 520];        // 24.96 KB
    __shared__ float pr_pair[192 * 8];     // 6 KB partials
    __shared__ float pr_o[192];
    __shared__ float pr_pt[96 * 3];

    {
        const float* src = ws_c + OFF_A + (size_t)i * (NH * N);
        for (int idx = t * 4; idx < NH * N; idx += 960 * 4) {
            float4 v = *(const float4*)&src[idx];
            int h = idx >> 9, j = idx & 511;
            *(float4*)&a_s[h * 520 + j] = v;
        }
    }
    __syncthreads();

    float* cat = ws + OFF_CAT + (size_t)i * 2112;

    float4 accA = {0,0,0,0}, accB = {0,0,0,0};   // o_pair
    float accO = 0.f;                            // o
    float g0 = 0.f, g1 = 0.f, g2 = 0.f;          // o_pt

    int jh = 0, v = 0;

    if (t < 384) {          // o_pair — 8 j per iter, all loads issued first
        jh = (t >= 192); v = t - jh * 192;
        const int cg = v & 31;
        const int hs = v >> 5;
        const float* zb = z + (size_t)i * N * CZ + cg * 4;
        const float* ahA = a_s + hs * 520;
        const float* ahB = a_s + (hs + 6) * 520;
        const int j0 = jh * 256;
        for (int jo = 0; jo < 256; jo += 8) {
            const int j = j0 + jo;
            float4 z0 = *(const float4*)&zb[(size_t)(j + 0) * CZ];
            float4 z1 = *(const float4*)&zb[(size_t)(j + 1) * CZ];
            float4 z2 = *(const float4*)&zb[(size_t)(j + 2) * CZ];
            float4 z3 = *(const float4*)&zb[(size_t)(j + 3) * CZ];
            float4 z4 = *(const float4*)&zb[(size_t)(j + 4) * CZ];
            float4 z5 = *(const float4*)&zb[(size_t)(j + 5) * CZ];
            float4 z6 = *(const float4*)&zb[(size_t)(j + 6) * CZ];
            float4 z7 = *(const float4*)&zb[(size_t)(j + 7) * CZ];
            float4 aA0 = *(const float4*)&ahA[j];
            float4 aA1 = *(const float4*)&ahA[j + 4];
            float4 aB0 = *(const float4*)&ahB[j];
            float4 aB1 = *(const float4*)&ahB[j + 4];
            accA.x += aA0.x * z0.x + aA0.y * z1.x + aA0.z * z2.x + aA0.w * z3.x
                    + aA1.x * z4.x + aA1.y * z5.x + aA1.z * z6.x + aA1.w * z7.x;
            accA.y += aA0.x * z0.y + aA0.y * z1.y + aA0.z * z2.y + aA0.w * z3.y
                    + aA1.x * z4.y + aA1.y * z5.y + aA1.z * z6.y + aA1.w * z7.y;
            accA.z += aA0.x * z0.z + aA0.y * z1.z + aA0.z * z2.z + aA0.w * z3.z
                    + aA1.x * z4.z + aA1.y * z5.z + aA1.z * z6.z + aA1.w * z7.z;
            accA.w += aA0.x * z0.w + aA0.y * z1.w + aA0.z * z2.w + aA0.w * z3.w
                    + aA1.x * z4.w + aA1.y * z5.w + aA1.z * z6.w + aA1.w * z7.w;
            accB.x += aB0.x * z0.x + aB0.y * z1.x + aB0.z * z2.x + aB0.w * z3.x
                    + aB1.x * z4.x + aB1.y * z5.x + aB1.z * z6.x + aB1.w * z7.x;
            accB.y += aB0.x * z0.y + aB0.y * z1.y + aB0.z * z2.y + aB0.w * z3.y
                    + aB1.x * z4.y + aB1.y * z5.y + aB1.z * z6.y + aB1.w * z7.y;
            accB.z += aB0.x * z0.z + aB0.y * z1.z + aB0.z * z2.z + aB0.w * z3.z
                    + aB1.x * z4.z + aB1.y * z5.z + aB1.z * z6.z + aB1.w * z7.z;
            accB.w += aB0.x * z0.w + aB0.y * z1.w + aB0.z * z2.w + aB0.w * z3.w
                    + aB1.x * z4.w + aB1.y * z5.w + aB1.z * z6.w + aB1.w * z7.w;
        }
    } else if (t < 768) {   // o — 8 scalar v loads in flight
        const int u = t - 384;
        jh = (u >= 192); v = u - jh * 192;
        const int h = v >> 4, cc = v & 15;
        const float* vcol = ws_c + OFF_V + h * 16 + cc;
        const float* ah = a_s + h * 520;
        const int j0 = jh * 256;
        for (int jo = 0; jo < 256; jo += 8) {
            const int j = j0 + jo;
            float v0 = vcol[(j + 0) * 192];
            float v1 = vcol[(j + 1) * 192];
            float v2 = vcol[(j + 2) * 192];
            float v3 = vcol[(j + 3) * 192];
            float v4 = vcol[(j + 4) * 192];
            float v5 = vcol[(j + 5) * 192];
            float v6 = vcol[(j + 6) * 192];
            float v7 = vcol[(j + 7) * 192];
            float4 a0 = *(const float4*)&ah[j];
            float4 a1 = *(const float4*)&ah[j + 4];
            accO += a0.x * v0 + a0.y * v1 + a0.z * v2 + a0.w * v3
                  + a1.x * v4 + a1.y * v5 + a1.z * v6 + a1.w * v7;
        }
    } else {                // o_pt (AoS) — 12 scalar loads in flight per 4 j
        const int u = t - 768;
        jh = (u >= 96); v = u - jh * 96;
        const int h = v >> 3, p = v & 7;
        const float* vp = ws_c + OFF_VPTS + (h * PV + p) * 3;
        const float* ah = a_s + h * 520;
        const int j0 = jh * 256;
        for (int jo = 0; jo < 256; jo += 4) {
            const int j = j0 + jo;
            const float* p0 = vp + (size_t)(j + 0) * 288;
            const float* p1 = vp + (size_t)(j + 1) * 288;
            const float* p2 = vp + (size_t)(j + 2) * 288;
            const float* p3 = vp + (size_t)(j + 3) * 288;
            float x0 = p0[0], y0 = p0[1], w0 = p0[2];
            float x1 = p1[0], y1 = p1[1], w1 = p1[2];
            float x2 = p2[0], y2 = p2[1], w2 = p2[2];
            float x3 = p3[0], y3 = p3[1], w3 = p3[2];
            float4 a4 = *(const float4*)&ah[j];
            g0 += a4.x * x0 + a4.y * x1 + a4.z * x2 + a4.w * x3;
            g1 += a4.x * y0 + a4.y * y1 + a4.z * y2 + a4.w * y3;
            g2 += a4.x * w0 + a4.y * w1 + a4.z * w2 + a4.w * w3;
        }
    }

    // half-1 publishes partials
    if (jh == 1) {
        if (t < 384) {
            float* d = pr_pair + v * 8;
            d[0] = accA.x; d[1] = accA.y; d[2] = accA.z; d[3] = accA.w;
            d[4] = accB.x; d[5] = accB.y; d[6] = accB.z; d[7] = accB.w;
        } else if (t < 768) {
            pr_o[v] = accO;
        } else {
            pr_pt[v * 3 + 0] = g0; pr_pt[v * 3 + 1] = g1; pr_pt[v * 3 + 2] = g2;
        }
    }
    __syncthreads();

    // half-0 combines + epilogue
    if (jh == 0) {
        if (t < 384) {
            const float* d = pr_pair + v * 8;
            accA.x += d[0]; accA.y += d[1]; accA.z += d[2]; accA.w += d[3];
            accB.x += d[4]; accB.y += d[5]; accB.z += d[6]; accB.w += d[7];
            const int cg = v & 31, hs = v >> 5;
            *(float4*)&cat[576 + hs * CZ + cg * 4]       = accA;
            *(float4*)&cat[576 + (hs + 6) * CZ + cg * 4] = accB;
        } else if (t < 768) {
            accO += pr_o[v];
            const int h = v >> 4, cc = v & 15;
            cat[h * 16 + cc] = accO;
        } else {
            g0 += pr_pt[v * 3 + 0]; g1 += pr_pt[v * 3 + 1]; g2 += pr_pt[v * 3 + 2];
            float R[9], ti[3];
            #pragma unroll
            for (int x = 0; x < 9; x++) R[x] = t_rots[i * 9 + x];
            #pragma unroll
            for (int x = 0; x < 3; x++) ti[x] = t_trans[i * 3 + x];
            g0 -= ti[0]; g1 -= ti[1]; g2 -= ti[2];
            float l0 = R[0] * g0 + R[3] * g1 + R[6] * g2;
            float l1 = R[1] * g0 + R[4] * g1 + R[7] * g2;
            float l2 = R[2] * g0 + R[5] * g1 + R[8] * g2;
            float nrm = sqrtf(l0 * l0 + l1 * l1 + l2 * l2 + 1e-8f);
            const int h = v >> 3, p = v & 7;
            int e = h * PV + p;
            cat[192 + e] = l0;
            cat[288 + e] = l1;
            cat[384 + e] = l2;
            cat[480 + e] = nrm;
        }
    }
}

// ---------------- kernel 6: out partials = cat @ Wout k-chunk (no atomics) ----------------
__global__ __launch_bounds__(384, 4) void out_kernel(
    const float* __restrict__ Wout, const float* __restrict__ ws_c,
    float* __restrict__ ws)
{
    const int rt = blockIdx.x;
    const int kc = blockIdx.y;
    const int t = threadIdx.x;
    __shared__ float ct[16 * 132];
    for (int idx = t * 4; idx < 16 * 132; idx += 384 * 4) {
        int rr = idx / 132, kk = idx % 132;
        *(float4*)&ct[idx] =
            *(const float4*)&ws_c[OFF_CAT + (size_t)(rt * 16 + rr) * 2112 + kc * 132 + kk];
    }
    __syncthreads();
    const int cq = t % 96, rg = t / 96;
    const int c0 = cq * 4;
    float acc[4][4] = {};
    const float* Wp = Wout + (size_t)kc * 132 * 384 + c0;
    #pragma unroll 4
    for (int kk = 0; kk < 132; kk += 4) {
        float4 w0 = *(const float4*)&Wp[(size_t)(kk + 0) * 384];
        float4 w1 = *(const float4*)&Wp[(size_t)(kk + 1) * 384];
        float4 w2 = *(const float4*)&Wp[(size_t)(kk + 2) * 384];
        float4 w3 = *(const float4*)&Wp[(size_t)(kk + 3) * 384];
        #pragma unroll
        for (int r = 0; r < 4; r++) {
            float4 sv = *(const float4*)&ct[(rg * 4 + r) * 132 + kk];
            acc[r][0] += sv.x * w0.x + sv.y * w1.x + sv.z * w2.x + sv.w * w3.x;
            acc[r][1] += sv.x * w0.y + sv.y * w1.y + sv.z * w2.y + sv.w * w3.y;
            acc[r][2] += sv.x * w0.z + sv.y * w1.z + sv.z * w2.z + sv.w * w3.z;
            acc[r][3] += sv.x * w0.w + sv.y * w1.w + sv.z * w2.w + sv.w * w3.w;
        }
    }
    float* dst = ws + OFF_A + (size_t)kc * (512 * 384);
    #pragma unroll
    for (int r = 0; r < 4; r++) {
        float4 a4 = make_float4(acc[r][0], acc[r][1], acc[r][2], acc[r][3]);
        *(float4*)&dst[(size_t)(rt * 16 + rg * 4 + r) * 384 + c0] = a4;
    }
}

// ---------------- kernel 7: out = bias + sum of 16 partials ----------------
__global__ __launch_bounds__(256) void reduce_out_kernel(
    const float* __restrict__ bout, const float* __restrict__ ws,
    float* __restrict__ out)
{
    const int idx = (blockIdx.x * 256 + threadIdx.x) * 4;   // float offset, < 512*384
    const int col = idx % 384;
    float4 acc = *(const float4*)&bout[col];
    #pragma unroll
    for (int kc = 0; kc < 16; kc++) {
        float4 p = *(const float4*)&ws[OFF_A + (size_t)kc * (512 * 384) + idx];
        acc.x += p.x; acc.y += p.y; acc.z += p.z; acc.w += p.w;
    }
    *(float4*)&out[idx] = acc;
}

extern "C" void kernel_launch(void* const* d_in, const int* in_sizes, int n_in,
                              void* d_out, int out_size, void* d_ws, size_t ws_size,
                              hipStream_t stream) {
    const float* s       = (const float*)d_in[0];
    const float* z       = (const float*)d_in[1];
    const float* t_trans = (const float*)d_in[2];
    const float* t_rots  = (const float*)d_in[3];
    const float* mask    = (const float*)d_in[4];
    const float* Wq      = (const float*)d_in[5];
    const float* bq      = (const float*)d_in[6];
    const float* Wkv     = (const float*)d_in[7];
    const float* bkv     = (const float*)d_in[8];
    const float* Wqp     = (const float*)d_in[9];
    const float* bqp     = (const float*)d_in[10];
    const float* Wkvp    = (const float*)d_in[11];
    const float* bkvp    = (const float*)d_in[12];
    const float* Wb      = (const float*)d_in[13];
    const float* bb      = (const float*)d_in[14];
    const float* hweights= (const float*)d_in[15];
    const float* Wout    = (const float*)d_in[16];
    const float* bout    = (const float*)d_in[17];
    float* ws  = (float*)d_ws;
    float* out = (float*)d_out;

    proj_kernel<<<dim3(32, 18), 256, 0, stream>>>(s, Wq, bq, Wkv, bkv, Wqp, bqp, Wkvp, bkvp, ws);
    point_kernel<<<512, 192, 0, stream>>>(t_trans, t_rots, ws);
    logitA_kernel<<<dim3(32, 32), 192, 0, stream>>>(mask, hweights, ws);
    bsoft_kernel<<<512, 512, 0, stream>>>(z, Wb, bb, ws);
    finish_kernel<<<512, 960, 0, stream>>>(z, t_trans, t_rots, ws, ws);
    out_kernel<<<dim3(32, 16), 384, 0, stream>>>(Wout, ws, ws);
    reduce_out_kernel<<<192, 256, 0, stream>>>(bout, ws, out);
}